// Round 1
// baseline (118.008 us; speedup 1.0000x reference)
//
#include <hip/hip_runtime.h>
#include <float.h>

static constexpr int NB_RED  = 2048;  // blocks in reduce pass (writes exactly this many partials)
static constexpr int NB_HIST = 1280;  // 5 blocks/CU * 256 CUs (32KB LDS/block -> 5 resident)
static constexpr int TPB     = 256;
static constexpr int NBINS   = 31;
static constexpr int NEDGES  = 32;

// d_ws layout (bytes):
//   [0,      16384)  double sums[2048]
//   [16384,  32768)  double sss [2048]
//   [32768,  40960)  float  mins[2048]
//   [40960,  49152)  float  maxs[2048]
//   [49152,  49280)  float  edges[32]
//   [49280,  49404)  uint   counts[31]

__global__ __launch_bounds__(TPB) void k_reduce(const float* __restrict__ a, long long n,
    double* __restrict__ sums, double* __restrict__ sss,
    float* __restrict__ mins, float* __restrict__ maxs) {
  const long long n4 = n >> 2;
  const float4* a4 = (const float4*)a;
  const int tid = threadIdx.x;
  long long gid = (long long)blockIdx.x * TPB + tid;
  const long long stride = (long long)gridDim.x * TPB;

  float mn = FLT_MAX, mx = -FLT_MAX;
  float s = 0.f, q = 0.f;
  for (long long i = gid; i < n4; i += stride) {
    float4 v = a4[i];
    mn = fminf(mn, fminf(fminf(v.x, v.y), fminf(v.z, v.w)));
    mx = fmaxf(mx, fmaxf(fmaxf(v.x, v.y), fmaxf(v.z, v.w)));
    s += v.x; s += v.y; s += v.z; s += v.w;
    q = fmaf(v.x, v.x, q); q = fmaf(v.y, v.y, q);
    q = fmaf(v.z, v.z, q); q = fmaf(v.w, v.w, q);
  }
  // scalar tail (n % 4), handled by one thread
  if (gid == 0) {
    for (long long i = n4 << 2; i < n; i++) {
      float x = a[i];
      mn = fminf(mn, x); mx = fmaxf(mx, x);
      s += x; q = fmaf(x, x, q);
    }
  }

  double sd = (double)s, qd = (double)q;
  // wave64 butterfly-free down-reduce
  #pragma unroll
  for (int off = 32; off > 0; off >>= 1) {
    mn = fminf(mn, __shfl_down(mn, off));
    mx = fmaxf(mx, __shfl_down(mx, off));
    sd += __shfl_down(sd, off);
    qd += __shfl_down(qd, off);
  }
  __shared__ float  smn[4], smx[4];
  __shared__ double ssd[4], sqd[4];
  const int wid = tid >> 6, lane = tid & 63;
  if (lane == 0) { smn[wid] = mn; smx[wid] = mx; ssd[wid] = sd; sqd[wid] = qd; }
  __syncthreads();
  if (tid == 0) {
    for (int w = 1; w < TPB / 64; w++) {
      smn[0] = fminf(smn[0], smn[w]); smx[0] = fmaxf(smx[0], smx[w]);
      ssd[0] += ssd[w]; sqd[0] += sqd[w];
    }
    mins[blockIdx.x] = smn[0]; maxs[blockIdx.x] = smx[0];
    sums[blockIdx.x] = ssd[0]; sss[blockIdx.x]  = sqd[0];
  }
}

__global__ __launch_bounds__(TPB) void k_finalize(
    const double* __restrict__ sums, const double* __restrict__ sss,
    const float* __restrict__ mins, const float* __restrict__ maxs,
    float* __restrict__ edges_ws, unsigned int* __restrict__ counts_ws,
    float* __restrict__ out, long long n) {
  const int tid = threadIdx.x;
  float mn = FLT_MAX, mx = -FLT_MAX;
  double sd = 0.0, qd = 0.0;
  for (int i = tid; i < NB_RED; i += TPB) {
    mn = fminf(mn, mins[i]); mx = fmaxf(mx, maxs[i]);
    sd += sums[i]; qd += sss[i];
  }
  #pragma unroll
  for (int off = 32; off > 0; off >>= 1) {
    mn = fminf(mn, __shfl_down(mn, off));
    mx = fmaxf(mx, __shfl_down(mx, off));
    sd += __shfl_down(sd, off);
    qd += __shfl_down(qd, off);
  }
  __shared__ float  smn[4], smx[4];
  __shared__ double ssd[4], sqd[4];
  const int wid = tid >> 6, lane = tid & 63;
  if (lane == 0) { smn[wid] = mn; smx[wid] = mx; ssd[wid] = sd; sqd[wid] = qd; }
  __syncthreads();
  __shared__ float r_mn, r_mx;
  __shared__ double r_s, r_q;
  if (tid == 0) {
    for (int w = 1; w < TPB / 64; w++) {
      smn[0] = fminf(smn[0], smn[w]); smx[0] = fmaxf(smx[0], smx[w]);
      ssd[0] += ssd[w]; sqd[0] += sqd[w];
    }
    r_mn = smn[0]; r_mx = smx[0]; r_s = ssd[0]; r_q = sqd[0];
  }
  __syncthreads();

  // edges = linspace(mn, mx, 32) with numpy semantics: i*step + mn, last = mx.
  // __fmul_rn/__fadd_rn keep separate rounding (no fma contraction), matching np.
  const float delta = (r_mx - r_mn) / 31.0f;
  if (tid < NEDGES) {
    float e = (tid == NEDGES - 1) ? r_mx
                                  : __fadd_rn(__fmul_rn((float)tid, delta), r_mn);
    edges_ws[tid] = e;
    out[5 + NBINS + tid] = e;   // edges at [36..68)
  }
  if (tid < NBINS) counts_ws[tid] = 0u;  // re-zero EVERY launch (graph replay safe)
  if (tid == 0) {
    out[0] = r_mn;
    out[1] = r_mx;
    out[2] = (float)n;        // 2^26, exact in fp32
    out[3] = (float)r_s;
    out[4] = (float)r_q;
  }
}

__global__ __launch_bounds__(TPB) void k_hist(const float* __restrict__ a, long long n,
    const float* __restrict__ edges_ws, unsigned int* __restrict__ counts_ws) {
  __shared__ float e_lds[NEDGES];            // 32 words = one per bank: conflict-free
  __shared__ unsigned int hist[TPB * NBINS]; // per-thread private; stride 31 -> 2-way alias (free)
  __shared__ unsigned int blk[NBINS];

  const int tid = threadIdx.x;
  if (tid < NEDGES) e_lds[tid] = edges_ws[tid];
  if (tid < NBINS)  blk[tid] = 0u;
  unsigned int* __restrict__ h = &hist[tid * NBINS];
  #pragma unroll
  for (int b = 0; b < NBINS; b++) h[b] = 0u;
  __syncthreads();

  const float mn = e_lds[0], mx = e_lds[NEDGES - 1];
  const float scale = 31.0f / (mx - mn);
  const float off0 = -mn * scale;

  const long long n4 = n >> 2;
  const float4* a4 = (const float4*)a;
  long long gid = (long long)blockIdx.x * TPB + tid;
  const long long stride = (long long)gridDim.x * TPB;
  const float EPS = 1e-3f;

  for (long long i = gid; i < n4; i += stride) {
    float4 v = a4[i];
    #pragma unroll
    for (int c = 0; c < 4; c++) {
      const float x = (c == 0) ? v.x : (c == 1) ? v.y : (c == 2) ? v.z : v.w;
      float t = fmaf(x, scale, off0);
      int bi = (int)t;                 // t >= -ulp, trunc == floor away from boundary
      float fr = t - (float)bi;
      // boundary window: fall back to exact searchsorted against the edge array
      bool near = (fr < EPS) | (fr > 1.0f - EPS) | (bi >= NBINS) | (t < 0.f);
      if (near) {
        int j = bi < 0 ? 0 : (bi > NEDGES - 1 ? NEDGES - 1 : bi);
        while (j < NEDGES - 1 && x >= e_lds[j + 1]) j++;  // largest j: edges[j] <= x
        while (j > 0 && x < e_lds[j]) j--;
        bi = j;                        // j == 31 (x == mx) -> dropped below
      }
      if (bi >= 0 && bi < NBINS) h[bi] += 1u;
    }
  }
  // scalar tail
  if (gid == 0) {
    for (long long i = n4 << 2; i < n; i++) {
      const float x = a[i];
      int j = 0;
      while (j < NEDGES - 1 && x >= e_lds[j + 1]) j++;
      while (j > 0 && x < e_lds[j]) j--;
      if (j < NBINS && x >= e_lds[0]) h[j] += 1u;
    }
  }
  __syncthreads();

  // fold 256 private histograms -> 31 block counters (rotated start: no same-addr storm)
  for (int k = 0; k < NBINS; k++) {
    const int b = (tid + k) % NBINS;
    const unsigned int c = hist[tid * NBINS + b];
    if (c) atomicAdd(&blk[b], c);
  }
  __syncthreads();
  if (tid < NBINS) {
    const unsigned int c = blk[tid];
    if (c) atomicAdd(&counts_ws[tid], c);
  }
}

__global__ void k_counts_out(const unsigned int* __restrict__ counts_ws,
                             float* __restrict__ out) {
  const int tid = threadIdx.x;
  if (tid < NBINS) {
    float f = (float)counts_ws[tid];
    if (tid == NBINS - 1) f += 1.0f;   // reference: counts.at[-1].add(1)
    out[5 + tid] = f;                  // counts at [5..36)
  }
}

extern "C" void kernel_launch(void* const* d_in, const int* in_sizes, int n_in,
                              void* d_out, int out_size, void* d_ws, size_t ws_size,
                              hipStream_t stream) {
  const float* a = (const float*)d_in[0];
  const long long n = (long long)in_sizes[0];
  char* ws = (char*)d_ws;
  double* sums = (double*)(ws);
  double* sss  = (double*)(ws + 16384);
  float*  mins = (float*)(ws + 32768);
  float*  maxs = (float*)(ws + 40960);
  float*  edges_ws = (float*)(ws + 49152);
  unsigned int* counts_ws = (unsigned int*)(ws + 49280);
  float* out = (float*)d_out;

  hipLaunchKernelGGL(k_reduce, dim3(NB_RED), dim3(TPB), 0, stream,
                     a, n, sums, sss, mins, maxs);
  hipLaunchKernelGGL(k_finalize, dim3(1), dim3(TPB), 0, stream,
                     sums, sss, mins, maxs, edges_ws, counts_ws, out, n);
  hipLaunchKernelGGL(k_hist, dim3(NB_HIST), dim3(TPB), 0, stream,
                     a, n, edges_ws, counts_ws);
  hipLaunchKernelGGL(k_counts_out, dim3(1), dim3(64), 0, stream,
                     counts_ws, out);
}

// Round 2
// 109.841 us; speedup vs baseline: 1.0744x; 1.0744x over previous
//
#include <hip/hip_runtime.h>
#include <float.h>

static constexpr int TPB    = 256;
static constexpr int NB1    = 1280;   // 5 blocks/CU * 256 CUs
static constexpr int NBUCK  = 8192;   // 13-bit key: sign + 8 exp + 4 mantissa bits
static constexpr int NBINS  = 31;
static constexpr int NEDGES = 32;

// d_ws layout (bytes):
//   [0,     32768)  uint   merged[8192]     (memset to 0 each launch)
//   [32768, 43008)  double sums[1280]
//   [43008, 53248)  double sss [1280]
//   [53248, 58368)  float  mins[1280]
//   [58368, 63488)  float  maxs[1280]

__global__ __launch_bounds__(TPB, 5) void k_pass1(
    const float* __restrict__ a, long long n,
    unsigned int* __restrict__ merged,
    double* __restrict__ sums, double* __restrict__ sss,
    float* __restrict__ mins, float* __restrict__ maxs) {
  __shared__ unsigned int hist[NBUCK];   // exactly 32 KiB
  const int tid = threadIdx.x;
  for (int i = tid; i < NBUCK; i += TPB) hist[i] = 0u;
  __syncthreads();

  const long long n4 = n >> 2;
  const float4* a4 = (const float4*)a;
  long long gid = (long long)blockIdx.x * TPB + tid;
  const long long stride = (long long)gridDim.x * TPB;

  float mn = FLT_MAX, mx = -FLT_MAX, s = 0.f, q = 0.f;
  for (long long i = gid; i < n4; i += stride) {
    float4 v = a4[i];
    #pragma unroll
    for (int c = 0; c < 4; c++) {
      const float x = (c == 0) ? v.x : (c == 1) ? v.y : (c == 2) ? v.z : v.w;
      mn = fminf(mn, x);
      mx = fmaxf(mx, x);
      s += x;
      q = fmaf(x, x, q);
      const unsigned key = (__float_as_uint(x) >> 19) & 0x1FFFu;
      atomicAdd(&hist[key], 1u);
    }
  }
  // scalar tail (n % 4)
  if (gid == 0) {
    for (long long i = n4 << 2; i < n; i++) {
      const float x = a[i];
      mn = fminf(mn, x); mx = fmaxf(mx, x);
      s += x; q = fmaf(x, x, q);
      atomicAdd(&hist[(__float_as_uint(x) >> 19) & 0x1FFFu], 1u);
    }
  }
  __syncthreads();

  // zero-skip merge of the block-private histogram into the global one
  for (int i = tid; i < NBUCK; i += TPB) {
    const unsigned c = hist[i];
    if (c) atomicAdd(&merged[i], c);
  }
  __syncthreads();   // everyone done reading hist -> safe to reuse as scratch

  // block stats reduce (scratch reuses the hist LDS)
  double sd = (double)s, qd = (double)q;
  #pragma unroll
  for (int off = 32; off > 0; off >>= 1) {
    mn = fminf(mn, __shfl_down(mn, off));
    mx = fmaxf(mx, __shfl_down(mx, off));
    sd += __shfl_down(sd, off);
    qd += __shfl_down(qd, off);
  }
  double* dsum = (double*)hist;          // hist[0..7]
  double* dss  = dsum + 4;               // hist[8..15]
  float*  fmn  = (float*)(hist + 16);    // hist[16..19]
  float*  fmx  = (float*)(hist + 20);    // hist[20..23]
  const int wid = tid >> 6, lane = tid & 63;
  if (lane == 0) { dsum[wid] = sd; dss[wid] = qd; fmn[wid] = mn; fmx[wid] = mx; }
  __syncthreads();
  if (tid == 0) {
    for (int w = 1; w < TPB / 64; w++) {
      fmn[0] = fminf(fmn[0], fmn[w]); fmx[0] = fmaxf(fmx[0], fmx[w]);
      dsum[0] += dsum[w]; dss[0] += dss[w];
    }
    mins[blockIdx.x] = fmn[0]; maxs[blockIdx.x] = fmx[0];
    sums[blockIdx.x] = dsum[0]; sss[blockIdx.x] = dss[0];
  }
}

// largest j with e[j] <= x, or -1
__device__ __forceinline__ int jloc_le(const float* e, float e0, float invd, float x) {
  float pos = (x - e0) * invd;
  int j = (int)fminf(fmaxf(pos, 0.0f), 31.0f);
  while (j < NEDGES - 1 && e[j + 1] <= x) j++;
  while (j >= 0 && e[j] > x) j--;
  return j;
}
// largest j with e[j] < x, or -1
__device__ __forceinline__ int jloc_lt(const float* e, float e0, float invd, float x) {
  float pos = (x - e0) * invd;
  int j = (int)fminf(fmaxf(pos, 0.0f), 31.0f);
  while (j < NEDGES - 1 && e[j + 1] < x) j++;
  while (j >= 0 && e[j] >= x) j--;
  return j;
}

__global__ __launch_bounds__(TPB) void k_post(
    const unsigned int* __restrict__ merged,
    const double* __restrict__ sums, const double* __restrict__ sss,
    const float* __restrict__ mins, const float* __restrict__ maxs,
    float* __restrict__ out, long long n) {
  __shared__ float e[NEDGES];
  __shared__ float r_mnmx[2];
  __shared__ double sred[8];
  __shared__ double cred[NBINS][4];
  const int tid = threadIdx.x;
  const int wid = tid >> 6, lane = tid & 63;

  // ---- stats reduce over 1280 block partials ----
  float mn = FLT_MAX, mx = -FLT_MAX;
  double sd = 0.0, qd = 0.0;
  for (int i = tid; i < NB1; i += TPB) {
    mn = fminf(mn, mins[i]); mx = fmaxf(mx, maxs[i]);
    sd += sums[i]; qd += sss[i];
  }
  #pragma unroll
  for (int off = 32; off > 0; off >>= 1) {
    mn = fminf(mn, __shfl_down(mn, off));
    mx = fmaxf(mx, __shfl_down(mx, off));
    sd += __shfl_down(sd, off);
    qd += __shfl_down(qd, off);
  }
  __shared__ float wmn[4], wmx[4];
  if (lane == 0) { wmn[wid] = mn; wmx[wid] = mx; sred[wid] = sd; sred[4 + wid] = qd; }
  __syncthreads();
  if (tid == 0) {
    for (int w = 1; w < TPB / 64; w++) {
      wmn[0] = fminf(wmn[0], wmn[w]); wmx[0] = fmaxf(wmx[0], wmx[w]);
      sred[0] += sred[w]; sred[4] += sred[4 + w];
    }
    r_mnmx[0] = wmn[0]; r_mnmx[1] = wmx[0];
    out[0] = wmn[0];
    out[1] = wmx[0];
    out[2] = (float)n;
    out[3] = (float)sred[0];
    out[4] = (float)sred[4];
  }
  __syncthreads();

  // ---- edges (numpy linspace semantics: i*delta + mn, last = mx) ----
  const float rmn = r_mnmx[0], rmx = r_mnmx[1];
  const float delta = (rmx - rmn) / 31.0f;
  if (tid < NEDGES) {
    float ev = (tid == NEDGES - 1) ? rmx
                                   : __fadd_rn(__fmul_rn((float)tid, delta), rmn);
    e[tid] = ev;
    out[5 + NBINS + tid] = ev;
  }
  __syncthreads();

  // ---- distribute 8192 buckets into 31 bins ----
  const float e0 = e[0];
  const float invd = 31.0f / (rmx - rmn);
  double cnt[NBINS];
  #pragma unroll
  for (int b = 0; b < NBINS; b++) cnt[b] = 0.0;

  for (int i = tid; i < NBUCK; i += TPB) {
    const unsigned c = merged[i];
    if (!c) continue;
    const unsigned m = i & 0xFFFu;
    const int sgn = i >> 12;
    const float lom = __uint_as_float(m << 19);
    const float him = (m == 0xFFFu) ? FLT_MAX : __uint_as_float((m + 1u) << 19);
    const float L = sgn ? -him : lom;
    const float H = sgn ? -lom : him;
    const int jL = jloc_le(e, e0, invd, L);
    const int jH = jloc_lt(e, e0, invd, H);
    if (jL == jH) {
      if (jL >= 0 && jL < NBINS) cnt[jL] += (double)c;   // bucket fully inside one bin: exact
    } else {
      const double w = (double)H - (double)L;
      const int j0 = jL > 0 ? jL : 0;
      const int j1 = jH < NBINS - 1 ? jH : NBINS - 1;
      for (int j = j0; j <= j1; j++) {
        const double lo = fmax((double)L, (double)e[j]);
        const double hi = fmin((double)H, (double)e[j + 1]);
        if (hi > lo) cnt[j] += (double)c * (hi - lo) / w;  // proportional split
      }
    }
  }

  // deterministic tree reduce of cnt[] across the block
  #pragma unroll
  for (int b = 0; b < NBINS; b++) {
    double v = cnt[b];
    #pragma unroll
    for (int off = 32; off > 0; off >>= 1) v += __shfl_down(v, off);
    if (lane == 0) cred[b][wid] = v;
  }
  __syncthreads();
  if (tid < NBINS) {
    double t = cred[tid][0] + cred[tid][1] + cred[tid][2] + cred[tid][3];
    if (tid == NBINS - 1) t += 1.0;    // reference: counts.at[-1].add(1)
    out[5 + tid] = (float)t;
  }
}

extern "C" void kernel_launch(void* const* d_in, const int* in_sizes, int n_in,
                              void* d_out, int out_size, void* d_ws, size_t ws_size,
                              hipStream_t stream) {
  const float* a = (const float*)d_in[0];
  const long long n = (long long)in_sizes[0];
  char* ws = (char*)d_ws;
  unsigned int* merged = (unsigned int*)(ws);
  double* sums = (double*)(ws + 32768);
  double* sss  = (double*)(ws + 43008);
  float*  mins = (float*)(ws + 53248);
  float*  maxs = (float*)(ws + 58368);
  float* out = (float*)d_out;

  hipMemsetAsync(merged, 0, NBUCK * sizeof(unsigned int), stream);
  hipLaunchKernelGGL(k_pass1, dim3(NB1), dim3(TPB), 0, stream,
                     a, n, merged, sums, sss, mins, maxs);
  hipLaunchKernelGGL(k_post, dim3(1), dim3(TPB), 0, stream,
                     merged, sums, sss, mins, maxs, out, n);
}